// Round 1
// baseline (150.634 us; speedup 1.0000x reference)
//
#include <hip/hip_runtime.h>
#include <hip/hip_bf16.h>

typedef __attribute__((ext_vector_type(8))) short short8;
typedef __attribute__((ext_vector_type(4))) float floatx4;

#define GLOBAL_AS __attribute__((address_space(1)))
#define LDS_AS __attribute__((address_space(3)))

// async 16B/lane global->LDS (dest = wave-uniform base + lane*16)
__device__ __forceinline__ void async_ld16(const void* g, void* l) {
  __builtin_amdgcn_global_load_lds((const GLOBAL_AS unsigned int*)g,
                                   (LDS_AS unsigned int*)l, 16, 0, 0);
}

__device__ __forceinline__ unsigned pack2_bf16(float a, float b) {
  __hip_bfloat162 h = __float22bfloat162_rn(make_float2(a, b));
  unsigned r;
  __builtin_memcpy(&r, &h, 4);
  return r;
}

// tanh + Legendre P1..P8, packed as the 8-bf16 MFMA A-fragment
__device__ __forceinline__ short8 legendre_frag(float xv) {
  // tanh(x) = 1 - 2/(exp(2x)+1); exp2 saturation handles |x| large correctly
  float e  = __builtin_amdgcn_exp2f(xv * 2.885390081777927f); // 2*log2(e)
  float t  = 1.0f - 2.0f * __builtin_amdgcn_rcpf(e + 1.0f);
  float p1 = t;
  float p2 = fmaf(1.5f * t, p1, -0.5f);
  float p3 = fmaf((5.0f / 3.0f) * t, p2, (-2.0f / 3.0f) * p1);
  float p4 = fmaf(1.75f * t, p3, -0.75f * p2);
  float p5 = fmaf(1.8f * t, p4, -0.8f * p3);
  float p6 = fmaf((11.0f / 6.0f) * t, p5, (-5.0f / 6.0f) * p4);
  float p7 = fmaf((13.0f / 7.0f) * t, p6, (-6.0f / 7.0f) * p5);
  float p8 = fmaf(1.875f * t, p7, -0.875f * p6);
  union { unsigned u[4]; short8 s; } r;
  r.u[0] = pack2_bf16(p1, p2);
  r.u[1] = pack2_bf16(p3, p4);
  r.u[2] = pack2_bf16(p5, p6);
  r.u[3] = pack2_bf16(p7, p8);
  return r.s;
}

#define MB 128        // batch rows per block
#define ICH 32        // n_in per chunk (K-chunk = 256)
#define NCH 8         // chunks (256/32)
#define BSTRIDE 264   // bt row stride in bf16 (256 + 8 pad, keeps 16B align)

__global__ __launch_bounds__(256, 2) void kan_kernel(
    const float* __restrict__ x, const float* __restrict__ cb,
    const float* __restrict__ bias, float* __restrict__ y) {
  __shared__ __align__(16) float xs[MB * ICH];             // 16 KB, xor-swizzled float4 blocks
  __shared__ __align__(16) unsigned short bt[64 * BSTRIDE]; // ~33 KB, Bt[o][k] bf16

  const int tid  = threadIdx.x;
  const int wid  = tid >> 6;
  const int lane = tid & 63;
  const int m    = lane & 15;   // MFMA row-in-tile / n-in-tile
  const int q    = lane >> 4;   // quad
  const int row_block = blockIdx.x * MB;

  floatx4 acc[2][4];
#pragma unroll
  for (int a = 0; a < 2; ++a)
#pragma unroll
    for (int nt = 0; nt < 4; ++nt) acc[a][nt] = (floatx4){0.f, 0.f, 0.f, 0.f};

  const int r0 = wid * 32 + m;  // local row, group a=0
  const int r1 = r0 + 16;       // group a=1
  const int x7 = m & 7;         // (r & 7) is the same for r0/r1

  for (int ch = 0; ch < NCH; ++ch) {
    __syncthreads();  // WAR guard on LDS from previous chunk

    // ---- stage x tile (128 rows x 32 cols fp32) via async global->LDS ----
    // slot s (float4 units): row r = s>>3, swizzled col c4s = s&7, source col = c4s ^ (r&7)
#pragma unroll
    for (int tcall = 0; tcall < 4; ++tcall) {
      int slot_base = (wid * 4 + tcall) * 64;
      int slot = slot_base + lane;
      int rr   = slot >> 3;
      int si4  = (slot & 7) ^ (rr & 7);
      const float* src = x + (size_t)(row_block + rr) * 256 + ch * ICH + si4 * 4;
      async_ld16(src, &xs[slot_base * 4]);
    }

    // ---- stage B chunk: c_basis[o][k] fp32 -> bf16 Bt[o][k] in LDS ----
#pragma unroll
    for (int u = 0; u < 16; ++u) {
      int idx = u * 256 + tid;      // 0..4095 float4 slots
      int o   = idx >> 6;
      int c4  = idx & 63;
      const float* s = cb + (size_t)o * 2048 + ch * 256 + c4 * 4;
      floatx4 v = *reinterpret_cast<const floatx4*>(s);
      uint2 w;
      w.x = pack2_bf16(v.x, v.y);
      w.y = pack2_bf16(v.z, v.w);
      *reinterpret_cast<uint2*>(&bt[o * BSTRIDE + c4 * 4]) = w;
    }
    __syncthreads();  // drains vmcnt (async x loads) + lgkmcnt (B writes)

    // ---- compute: 8 K-steps of 16x16x32 ----
#pragma unroll
    for (int ks = 0; ks < 8; ++ks) {
      short8 fb[4];
#pragma unroll
      for (int nt = 0; nt < 4; ++nt) {
        fb[nt] = *reinterpret_cast<const short8*>(
            &bt[(nt * 16 + m) * BSTRIDE + ks * 32 + q * 8]);
      }
      // lane computes basis for (row, i = ch*32 + ks*4 + q): its A-frag directly
      float xv0 = xs[r0 * 32 + ((ks ^ x7) << 2) + q];
      float xv1 = xs[r1 * 32 + ((ks ^ x7) << 2) + q];
      short8 fa0 = legendre_frag(xv0);
      short8 fa1 = legendre_frag(xv1);
#pragma unroll
      for (int nt = 0; nt < 4; ++nt) {
        acc[0][nt] = __builtin_amdgcn_mfma_f32_16x16x32_bf16(fa0, fb[nt], acc[0][nt], 0, 0, 0);
        acc[1][nt] = __builtin_amdgcn_mfma_f32_16x16x32_bf16(fa1, fb[nt], acc[1][nt], 0, 0, 0);
      }
    }
  }

  // ---- epilogue: D[row=(q*4+reg)][col=m], add bias ----
  float bv[4];
#pragma unroll
  for (int nt = 0; nt < 4; ++nt) bv[nt] = bias[nt * 16 + m];
#pragma unroll
  for (int a = 0; a < 2; ++a) {
    int gr0 = row_block + wid * 32 + a * 16 + q * 4;
#pragma unroll
    for (int nt = 0; nt < 4; ++nt) {
#pragma unroll
      for (int r = 0; r < 4; ++r) {
        y[(size_t)(gr0 + r) * 64 + nt * 16 + m] = acc[a][nt][r] + bv[nt];
      }
    }
  }
}

extern "C" void kernel_launch(void* const* d_in, const int* in_sizes, int n_in,
                              void* d_out, int out_size, void* d_ws, size_t ws_size,
                              hipStream_t stream) {
  const float* x    = (const float*)d_in[0];
  const float* cb   = (const float*)d_in[1];
  const float* bias = (const float*)d_in[2];
  float* y = (float*)d_out;
  int batch = in_sizes[0] / 256;   // 65536
  dim3 grid(batch / MB), block(256);
  hipLaunchKernelGGL(kan_kernel, grid, block, 0, stream, x, cb, bias, y);
}

// Round 3
// 127.666 us; speedup vs baseline: 1.1799x; 1.1799x over previous
//
#include <hip/hip_runtime.h>
#include <hip/hip_bf16.h>

typedef __attribute__((ext_vector_type(8))) short short8;
typedef __attribute__((ext_vector_type(4))) float floatx4;
typedef __attribute__((ext_vector_type(4))) unsigned int uintx4;

#define GLOBAL_AS __attribute__((address_space(1)))
#define LDS_AS __attribute__((address_space(3)))

// async 16B/lane global->LDS. CAUTION: LDS dest = WAVE-uniform base + lane*16.
__device__ __forceinline__ void async_ld16(const void* g, void* l) {
  __builtin_amdgcn_global_load_lds((const GLOBAL_AS unsigned int*)g,
                                   (LDS_AS unsigned int*)l, 16, 0, 0);
}

__device__ __forceinline__ unsigned pack2_bf16(float a, float b) {
  __hip_bfloat162 h = __float22bfloat162_rn(make_float2(a, b));
  unsigned r;
  __builtin_memcpy(&r, &h, 4);
  return r;
}

// tanh + Legendre P1..P8, packed as the 8-bf16 MFMA A-fragment
__device__ __forceinline__ short8 legendre_frag(float xv) {
  float e  = __builtin_amdgcn_exp2f(xv * 2.885390081777927f); // 2*log2(e)
  float t  = 1.0f - 2.0f * __builtin_amdgcn_rcpf(e + 1.0f);
  float p1 = t;
  float p2 = fmaf(1.5f * t, p1, -0.5f);
  float p3 = fmaf((5.0f / 3.0f) * t, p2, (-2.0f / 3.0f) * p1);
  float p4 = fmaf(1.75f * t, p3, -0.75f * p2);
  float p5 = fmaf(1.8f * t, p4, -0.8f * p3);
  float p6 = fmaf((11.0f / 6.0f) * t, p5, (-5.0f / 6.0f) * p4);
  float p7 = fmaf((13.0f / 7.0f) * t, p6, (-6.0f / 7.0f) * p5);
  float p8 = fmaf(1.875f * t, p7, -0.875f * p6);
  union { unsigned u[4]; short8 s; } r;
  r.u[0] = pack2_bf16(p1, p2);
  r.u[1] = pack2_bf16(p3, p4);
  r.u[2] = pack2_bf16(p5, p6);
  r.u[3] = pack2_bf16(p7, p8);
  return r.s;
}

// ---- kernel 1: convert c_basis fp32 -> bf16 into ws, per-chunk transposed ----
// ws layout (shorts): ws[ch][i_local][o][d], ch=i>>5, i_local=i&31  (256 KB total)
__global__ void conv_kernel(const float* __restrict__ cb, unsigned short* __restrict__ ws) {
  int t = blockIdx.x * 256 + threadIdx.x;   // 0..16383 = (o,i)
  int o = t >> 8;
  int i = t & 255;
  const floatx4* s = (const floatx4*)(cb + ((size_t)o * 256 + i) * 8);
  floatx4 v0 = s[0], v1 = s[1];
  uintx4 w;
  w.x = pack2_bf16(v0.x, v0.y);
  w.y = pack2_bf16(v0.z, v0.w);
  w.z = pack2_bf16(v1.x, v1.y);
  w.w = pack2_bf16(v1.z, v1.w);
  *(uintx4*)(ws + (size_t)(i >> 5) * 16384 + (i & 31) * 512 + o * 8) = w;
}

// ---- kernel 2: main. 128 threads (2 waves), 64 rows/block, grid 1024 (4 blk/CU) ----
#define MB 64
#define NCH 8

__global__ __launch_bounds__(128, 2) void kan_kernel(
    const float* __restrict__ x, const unsigned short* __restrict__ ws,
    const float* __restrict__ bias, float* __restrict__ y) {
  __shared__ __align__(16) float xs[MB * 32];              // 8 KB, xor-swizzled float4 blocks
  __shared__ __align__(16) unsigned short bt[32 * 64 * 8]; // 32 KB, btT[g=i_local][o][d]

  const int tid  = threadIdx.x;
  const int wid  = tid >> 6;    // 0..1
  const int lane = tid & 63;
  const int m    = lane & 15;
  const int q    = lane >> 4;
  const int row_block = blockIdx.x * MB;

  floatx4 acc[2][4];
#pragma unroll
  for (int a = 0; a < 2; ++a)
#pragma unroll
    for (int nt = 0; nt < 4; ++nt) acc[a][nt] = (floatx4){0.f, 0.f, 0.f, 0.f};

  const int r0 = wid * 32 + m;                      // rows r0, r0+16
  // xv byte-offset bases; in-loop addr = base ^ (ks<<4)  (bits 4..6 are free)
  const int xb0 = r0 * 128 + ((m & 7) << 4) + q * 4;
  const int xb1 = xb0 + 16 * 128;
  // B-frag base: single vaddr, all 32 reads/chunk use uniform immediate offsets
  const unsigned short* btbase = &bt[(q * 64 + m) * 8];

  // precompute staging source pointers (advance per chunk)
  const float* xsrc[4];
#pragma unroll
  for (int t = 0; t < 4; ++t) {
    int slot = (wid * 4 + t) * 64 + lane;
    int rr   = slot >> 3;
    int si4  = (slot & 7) ^ (rr & 7);
    xsrc[t] = x + (size_t)(row_block + rr) * 256 + si4 * 4;
  }
  // B source: per-WAVE lane pointer so source slot == dest slot (wave-uniform base rule)
  const unsigned short* bsrc = ws + (size_t)(wid * 64 + lane) * 8;

  for (int ch = 0; ch < NCH; ++ch) {
    __syncthreads();  // WAR guard on LDS

    // stage x tile (64 rows x 32 cols fp32): 512 float4 slots
#pragma unroll
    for (int t = 0; t < 4; ++t) {
      int slot_base = (wid * 4 + t) * 64;
      async_ld16(xsrc[t], &xs[slot_base * 4]);
      xsrc[t] += 32;
    }
    // stage B chunk (32 KB bf16, pre-transposed in ws): 2048 16B slots
    // dest slot = t*128 + wid*64 + lane; source built identically
#pragma unroll
    for (int t = 0; t < 16; ++t) {
      int slot_base = t * 128 + wid * 64;
      async_ld16(bsrc + (size_t)ch * 16384 + (size_t)t * 1024, &bt[slot_base * 8]);
    }
    __syncthreads();  // drains vmcnt

    // compute: 8 K-steps of 16x16x32
#pragma unroll
    for (int ks = 0; ks < 8; ++ks) {
      short8 fb[4];
#pragma unroll
      for (int nt = 0; nt < 4; ++nt) {
        fb[nt] = *(const short8*)(btbase + ks * 2048 + nt * 128);
      }
      float xv0 = *(const float*)((const char*)xs + (xb0 ^ (ks << 4)));
      float xv1 = *(const float*)((const char*)xs + (xb1 ^ (ks << 4)));
      short8 fa0 = legendre_frag(xv0);
      short8 fa1 = legendre_frag(xv1);
#pragma unroll
      for (int nt = 0; nt < 4; ++nt) {
        acc[0][nt] = __builtin_amdgcn_mfma_f32_16x16x32_bf16(fa0, fb[nt], acc[0][nt], 0, 0, 0);
        acc[1][nt] = __builtin_amdgcn_mfma_f32_16x16x32_bf16(fa1, fb[nt], acc[1][nt], 0, 0, 0);
      }
    }
  }

  // epilogue: D[row=(q*4+reg)][col=m], add bias
  float bv[4];
#pragma unroll
  for (int nt = 0; nt < 4; ++nt) bv[nt] = bias[nt * 16 + m];
#pragma unroll
  for (int a = 0; a < 2; ++a) {
    int gr0 = row_block + wid * 32 + a * 16 + q * 4;
#pragma unroll
    for (int nt = 0; nt < 4; ++nt) {
#pragma unroll
      for (int r = 0; r < 4; ++r) {
        y[(size_t)(gr0 + r) * 64 + nt * 16 + m] = acc[a][nt][r] + bv[nt];
      }
    }
  }
}

extern "C" void kernel_launch(void* const* d_in, const int* in_sizes, int n_in,
                              void* d_out, int out_size, void* d_ws, size_t ws_size,
                              hipStream_t stream) {
  const float* x    = (const float*)d_in[0];
  const float* cb   = (const float*)d_in[1];
  const float* bias = (const float*)d_in[2];
  float* y = (float*)d_out;
  unsigned short* ws = (unsigned short*)d_ws;
  int batch = in_sizes[0] / 256;  // 65536
  hipLaunchKernelGGL(conv_kernel, dim3(64), dim3(256), 0, stream, cb, ws);
  hipLaunchKernelGGL(kan_kernel, dim3(batch / MB), dim3(128), 0, stream, x, ws, bias, y);
}